// Round 8
// baseline (592.172 us; speedup 1.0000x reference)
//
#include <hip/hip_runtime.h>

// LDPC BP decoder, (3,6)-regular. 1 WG = 1 batch element, 1024 threads.
// Edge e (vn order) = 3v+j; c = e mod 8192; cn-order slot q = 6c+t, e = c+8192t.
// Thread owns CNs c = tid + 1024*i (i=0..7); messages f32 in registers
// (fully static-indexed). Reference f32 op chain replicated literally;
// exp/log are lean f64 implementations (>=2^-39 internal, ~CR f32).
//
// r4-r7 lesson: RA budget pinned at 64 VGPR; spills = scheduler interleaving
// multiple f64 phi chains (peak live ~72). sched_barrier(0) after each phi
// caps the overlap -> peak ~62 fits 64. No FP-semantics change.

constexpr int NUM_VNS  = 16384;
constexpr int NUM_ITER = 8;
constexpr float LLR_MAX  = 20.0f;
constexpr float PHI_MIN  = 8.5e-8f;
constexpr float PHI_MAX  = 16.635532f;

#define THREADS 1024

// exp(x) for x in [0, 16.64]; internal rel err ~2^-42.
__device__ __forceinline__ double lean_exp(double x) {
    double t = x * 1.4426950408889634;
    double k = __builtin_rint(t);
    double r = __builtin_fma(-k, 0.6931471805599453, x);
    r = __builtin_fma(-k, 2.3190468138462996e-17, r);
    double p = 1.0 / 3628800.0;                  // Taylor deg 10, |r|<=0.347
    p = __builtin_fma(p, r, 1.0 / 362880.0);
    p = __builtin_fma(p, r, 1.0 / 40320.0);
    p = __builtin_fma(p, r, 1.0 / 5040.0);
    p = __builtin_fma(p, r, 1.0 / 720.0);
    p = __builtin_fma(p, r, 1.0 / 120.0);
    p = __builtin_fma(p, r, 1.0 / 24.0);
    p = __builtin_fma(p, r, 1.0 / 6.0);
    p = __builtin_fma(p, r, 0.5);
    p = __builtin_fma(p, r, 1.0);
    p = __builtin_fma(p, r, 1.0);
    int ik = (int)k;                              // k in [0,24]
    double s = __hiloint2double((1023 + ik) << 20, 0);
    return p * s;
}

// log(v) for v in [2^-23, 2^25], v an exact f32 value; abs err ~2^-40.
__device__ __forceinline__ double lean_log(double v) {
    int hv = __double2hiint(v);
    int lv = __double2loint(v);
    int e  = (hv >> 20) - 1023;
    double m = __hiloint2double((hv & 0x000FFFFF) | 0x3FF00000, lv);
    if (m >= 1.4142135623730951) { m *= 0.5; e += 1; }   // m in [0.7071,1.4142)
    double t = m - 1.0;
    double d = t + 2.0;
    // u = t/d via f32-rcp seed + 1 f64 Newton step (err ~seed^2 ~2^-45)
    double r = (double)__builtin_amdgcn_rcpf((float)d);
    r = __builtin_fma(__builtin_fma(-d, r, 1.0), r, r);
    double u = t * r;
    double w = u * u;                             // w <= 0.0295
    double P = 2.0 / 13.0;                        // 2*artanh: deg 6 in w
    P = __builtin_fma(P, w, 2.0 / 11.0);
    P = __builtin_fma(P, w, 2.0 / 9.0);
    P = __builtin_fma(P, w, 2.0 / 7.0);
    P = __builtin_fma(P, w, 2.0 / 5.0);
    P = __builtin_fma(P, w, 2.0 / 3.0);
    P = __builtin_fma(P, w, 2.0);
    double lm = u * P;
    return __builtin_fma((double)e, 0.6931471805599453, lm);
}

// literal reference chain: clip; ex=f32(exp); a=ex+1, b=ex-1 in f32;
// la=f32(log a), lb=f32(log b); return la-lb.
__device__ __forceinline__ float phi_f(float xf) {
    xf = fminf(fmaxf(xf, PHI_MIN), PHI_MAX);
    float exf = (float)lean_exp((double)xf);
    float af = exf + 1.0f;
    float bf = exf - 1.0f;
    float la = (float)lean_log((double)af);
    float lb = (float)lean_log((double)bf);
    return la - lb;
}

__global__ __launch_bounds__(THREADS)
void ldpc_bp_kernel(const float* __restrict__ llr_ch, float* __restrict__ out)
{
    __shared__ float buf[24576];    // 96 KB: one half of the edges (3 t-blocks)
    __shared__ float vtot[NUM_VNS]; // 64 KB

    const int b   = blockIdx.x;
    const int tid = threadIdx.x;
    const float* __restrict__ llr_b = llr_ch + (size_t)b * NUM_VNS;

    float msg[6][8];   // msg[t][i], edge e = (tid+1024i) + 8192t  (static idx only!)
#pragma unroll
    for (int t = 0; t < 6; ++t)
#pragma unroll
        for (int i = 0; i < 8; ++i) msg[t][i] = 0.0f;

    for (int iter = 0; iter <= NUM_ITER; ++iter) {
        // LICM fence: stop the compiler hoisting the llr loads into registers.
        unsigned long long lbase = (unsigned long long)llr_b;
        asm volatile("" : "+s"(lbase));
        const float* __restrict__ lp = (const float*)lbase;

        // ---- A: stage t-blocks 0..2 into buf[e] ----
#pragma unroll
        for (int t = 0; t < 3; ++t)
#pragma unroll
            for (int i = 0; i < 8; ++i)
                buf[(t << 13) + tid + THREADS * i] = msg[t][i];
        __syncthreads();

        // ---- B: vtot for v in [0,8192), exact order ((m0+m1)+m2)-x ----
#pragma unroll
        for (int k = 0; k < 8; ++k) {
            int v = tid + THREADS * k;
            float x = lp[v];
            x = fminf(fmaxf(x, -LLR_MAX), LLR_MAX);
            int e = 3 * v;
            vtot[v] = ((buf[e] + buf[e + 1]) + buf[e + 2]) - x;
        }
        __syncthreads();

        // ---- C: stage t-blocks 3..5 ----
#pragma unroll
        for (int t = 0; t < 3; ++t)
#pragma unroll
            for (int i = 0; i < 8; ++i)
                buf[(t << 13) + tid + THREADS * i] = msg[t + 3][i];
        __syncthreads();

        // ---- D: vtot for v in [8192,16384) ----
#pragma unroll
        for (int k = 8; k < 16; ++k) {
            int v = tid + THREADS * k;
            float x = lp[v];
            x = fminf(fmaxf(x, -LLR_MAX), LLR_MAX);
            int e = 3 * v - 24576;
            vtot[v] = ((buf[e] + buf[e + 1]) + buf[e + 2]) - x;
        }
        __syncthreads();

        if (iter == NUM_ITER) break;

        // ---- E: CN update, literal reference chain, fully unrolled.
        //      msg[t][i] reused as mag storage; sched_barrier(0) after each
        //      phi keeps one f64 chain live at a time (spill kill). ----
#pragma unroll
        for (int i = 0; i < 8; ++i) {
            int c = tid + THREADS * i;
            unsigned sb = 0u;
#pragma unroll
            for (int t = 0; t < 6; ++t) {
                int e = c + (t << 13);
                int v = (int)(((unsigned)e * 43691u) >> 17);   // e/3
                float m = vtot[v] - msg[t][i];                 // vn-extrinsic
                if (m < 0.0f) sb |= (1u << t);                 // sign(0) -> +1
                msg[t][i] = phi_f(fabsf(m));                   // mag in place
                __builtin_amdgcn_sched_barrier(0);
            }
            float ms = ((((msg[0][i] + msg[1][i]) + msg[2][i]) + msg[3][i])
                        + msg[4][i]) + msg[5][i];
            unsigned all6 = __popc(sb) & 1u;
#pragma unroll
            for (int t = 0; t < 6; ++t) {
                float o = phi_f(ms - msg[t][i]);
                unsigned flip = all6 ^ ((sb >> t) & 1u);
                msg[t][i] = flip ? -o : o;
                __builtin_amdgcn_sched_barrier(0);
            }
        }
        __syncthreads();
    }

    // ---- marginalize: out[b][v] = -vtot[v] ----
#pragma unroll
    for (int k = 0; k < 16; ++k) {
        int v = tid + THREADS * k;
        out[(size_t)b * NUM_VNS + v] = -vtot[v];
    }
}

extern "C" void kernel_launch(void* const* d_in, const int* in_sizes, int n_in,
                              void* d_out, int out_size, void* d_ws, size_t ws_size,
                              hipStream_t stream) {
    const float* llr_ch = (const float*)d_in[0];
    float* out = (float*)d_out;
    ldpc_bp_kernel<<<dim3(128), dim3(THREADS), 0, stream>>>(llr_ch, out);
}

// Round 9
// 588.691 us; speedup vs baseline: 1.0059x; 1.0059x over previous
//
#include <hip/hip_runtime.h>

// LDPC BP decoder, (3,6)-regular. 1 WG = 1 batch element, 1024 threads.
// Edge e (vn order) = 3v+j; c = e mod 8192; cn-order slot q = 6c+t, e = c+8192t.
//
// r4-r8 lesson: RA budget pinned at 64 VGPR; 48 persistent msg regs + phi
// working set spilled ~6 dwords/thread/iter (25.6 MB scratch each way).
// Fix: msgs t0-2 live permanently in LDS buf[e] (96 KB, already edge-ordered
// for the VN phase), only t3-5 in regs (24). vtot-upper pipelines through a
// 32 KB window; straddle VNs (10922, 13653) done by thread 0 (own regs+shfl).
// FP chain bit-identical to r7 (absmax 0.25).

constexpr int NUM_VNS  = 16384;
constexpr int NUM_ITER = 8;
constexpr float LLR_MAX  = 20.0f;
constexpr float PHI_MIN  = 8.5e-8f;
constexpr float PHI_MAX  = 16.635532f;

#define THREADS 1024

// exp(x) for x in [0, 16.64]; internal rel err ~2^-42.
__device__ __forceinline__ double lean_exp(double x) {
    double t = x * 1.4426950408889634;
    double k = __builtin_rint(t);
    double r = __builtin_fma(-k, 0.6931471805599453, x);
    r = __builtin_fma(-k, 2.3190468138462996e-17, r);
    double p = 1.0 / 3628800.0;                  // Taylor deg 10, |r|<=0.347
    p = __builtin_fma(p, r, 1.0 / 362880.0);
    p = __builtin_fma(p, r, 1.0 / 40320.0);
    p = __builtin_fma(p, r, 1.0 / 5040.0);
    p = __builtin_fma(p, r, 1.0 / 720.0);
    p = __builtin_fma(p, r, 1.0 / 120.0);
    p = __builtin_fma(p, r, 1.0 / 24.0);
    p = __builtin_fma(p, r, 1.0 / 6.0);
    p = __builtin_fma(p, r, 0.5);
    p = __builtin_fma(p, r, 1.0);
    p = __builtin_fma(p, r, 1.0);
    int ik = (int)k;                              // k in [0,24]
    double s = __hiloint2double((1023 + ik) << 20, 0);
    return p * s;
}

// log(v) for v in [2^-23, 2^25], v an exact f32 value; abs err ~2^-40.
__device__ __forceinline__ double lean_log(double v) {
    int hv = __double2hiint(v);
    int lv = __double2loint(v);
    int e  = (hv >> 20) - 1023;
    double m = __hiloint2double((hv & 0x000FFFFF) | 0x3FF00000, lv);
    if (m >= 1.4142135623730951) { m *= 0.5; e += 1; }   // m in [0.7071,1.4142)
    double t = m - 1.0;
    double d = t + 2.0;
    double r = (double)__builtin_amdgcn_rcpf((float)d);
    r = __builtin_fma(__builtin_fma(-d, r, 1.0), r, r);
    double u = t * r;
    double w = u * u;                             // w <= 0.0295
    double P = 2.0 / 13.0;                        // 2*artanh: deg 6 in w
    P = __builtin_fma(P, w, 2.0 / 11.0);
    P = __builtin_fma(P, w, 2.0 / 9.0);
    P = __builtin_fma(P, w, 2.0 / 7.0);
    P = __builtin_fma(P, w, 2.0 / 5.0);
    P = __builtin_fma(P, w, 2.0 / 3.0);
    P = __builtin_fma(P, w, 2.0);
    double lm = u * P;
    return __builtin_fma((double)e, 0.6931471805599453, lm);
}

__device__ __forceinline__ float phi_f(float xf) {
    xf = fminf(fmaxf(xf, PHI_MIN), PHI_MAX);
    float exf = (float)lean_exp((double)xf);
    float af = exf + 1.0f;
    float bf = exf - 1.0f;
    float la = (float)lean_log((double)af);
    float lb = (float)lean_log((double)bf);
    return la - lb;
}

__global__ __launch_bounds__(THREADS)
void ldpc_bp_kernel(const float* __restrict__ llr_ch, float* __restrict__ out)
{
    __shared__ float buf[24576];   // 96 KB: msgs/mags t0-2, resident, buf[c+8192t]
    __shared__ float sh32[8192];   // 32 KB: vtot lower, then vtot upper (v-8192)
    __shared__ float W[8192];      // 32 KB: staging window for t3/t4/t5

    const int b   = blockIdx.x;
    const int tid = threadIdx.x;
    const float* __restrict__ llr_b = llr_ch + (size_t)b * NUM_VNS;
    float* __restrict__ out_b = out + (size_t)b * NUM_VNS;

    float msg[3][8];               // t3..t5 messages (mags during E), static idx
    float ms[8];                   // per-CN mag_sum accumulators
    unsigned sbA = 0u, sbB = 0u;   // sign bits: CN i, edge t -> bit (i&3)*6+t

#pragma unroll
    for (int t = 0; t < 3; ++t)
#pragma unroll
        for (int i = 0; i < 8; ++i) {
            buf[(t << 13) + tid + THREADS * i] = 0.0f;
            msg[t][i] = 0.0f;
        }

    for (int iter = 0; iter <= NUM_ITER; ++iter) {
        const bool last = (iter == NUM_ITER);
        unsigned long long lbase = (unsigned long long)llr_b;
        asm volatile("" : "+s"(lbase));       // LICM fence on llr loads
        const float* lp = (const float*)lbase;

        __syncthreads();                      // prev msg writes -> B reads
        // ---- B: vtot lower, v in [0,8192), from resident buf ----
#pragma unroll
        for (int k = 0; k < 8; ++k) {
            int v = tid + THREADS * k;
            float x = fminf(fmaxf(lp[v], -LLR_MAX), LLR_MAX);
            int e = 3 * v;
            float s = ((buf[e] + buf[e + 1]) + buf[e + 2]) - x;
            if (last) out_b[v] = -s; else sh32[v] = s;
        }
        __syncthreads();

        // ---- E-low (t=0..2, mags in place in buf)  ||  stage t3 -> W ----
#pragma unroll
        for (int i = 0; i < 8; ++i) W[tid + THREADS * i] = msg[0][i];
        if (!last) {
            sbA = 0u; sbB = 0u;
#pragma unroll
            for (int i = 0; i < 8; ++i) {
                int c = tid + THREADS * i;
                float acc = 0.0f;
#pragma unroll
                for (int t = 0; t < 3; ++t) {
                    int e = c + (t << 13);
                    int v = (int)(((unsigned)e * 43691u) >> 17);   // e/3
                    float old = buf[e];
                    float m = sh32[v] - old;
                    unsigned neg = (m < 0.0f) ? 1u : 0u;
                    unsigned bit = neg << ((unsigned)(i & 3) * 6 + t);
                    if (i < 4) sbA |= bit; else sbB |= bit;
                    float mg = phi_f(fabsf(m));
                    buf[e] = mg;                                   // mag in place
                    acc = (t == 0) ? mg : (acc + mg);
                    __builtin_amdgcn_sched_barrier(0);
                }
                ms[i] = acc;
            }
        }
        __syncthreads();

        // ---- chunk t3: vtot for v in [8192,10922) + thread0: v=10922 ----
#pragma unroll
        for (int k = 0; k < 3; ++k) {
            int r = tid + THREADS * k;
            if (r < 2730) {
                int v = 8192 + r;
                float x = fminf(fmaxf(lp[v], -LLR_MAX), LLR_MAX);
                int j = 3 * r;
                float s = ((W[j] + W[j + 1]) + W[j + 2]) - x;
                if (last) out_b[v] = -s; else sh32[r] = s;
            }
        }
        if (tid == 0) {   // v=10922: edges t3 c8190,c8191 + t4 c0 (own reg)
            float x = fminf(fmaxf(lp[10922], -LLR_MAX), LLR_MAX);
            float s = ((W[8190] + W[8191]) + msg[1][0]) - x;
            if (last) out_b[10922] = -s; else sh32[2730] = s;
        }
        __syncthreads();

        // ---- E-t3  ||  stage t4 -> W ----
#pragma unroll
        for (int i = 0; i < 8; ++i) W[tid + THREADS * i] = msg[1][i];
        if (!last) {
#pragma unroll
            for (int i = 0; i < 8; ++i) {
                int c = tid + THREADS * i;
                int e = c + 24576;
                int v = (int)(((unsigned)e * 43691u) >> 17);
                float m = sh32[v - 8192] - msg[0][i];
                unsigned neg = (m < 0.0f) ? 1u : 0u;
                unsigned bit = neg << ((unsigned)(i & 3) * 6 + 3);
                if (i < 4) sbA |= bit; else sbB |= bit;
                float mg = phi_f(fabsf(m));
                msg[0][i] = mg;
                ms[i] = ms[i] + mg;
                __builtin_amdgcn_sched_barrier(0);
            }
        }
        __syncthreads();

        // ---- chunk t4: v in [10923,13653) + thread0: v=13653 ----
        {
            float t5c1 = __shfl(msg[2][0], 1);   // t5 c=1 lives in lane 1 (i=0)
#pragma unroll
            for (int k = 0; k < 3; ++k) {
                int r = tid + THREADS * k;
                if (r < 2730) {
                    int v = 10923 + r;
                    float x = fminf(fmaxf(lp[v], -LLR_MAX), LLR_MAX);
                    int j = 3 * r + 1;
                    float s = ((W[j] + W[j + 1]) + W[j + 2]) - x;
                    if (last) out_b[v] = -s; else sh32[2731 + r] = s;
                }
            }
            if (tid == 0) {  // v=13653: t4 c8191 (W) + t5 c0 (own) + t5 c1 (shfl)
                float x = fminf(fmaxf(lp[13653], -LLR_MAX), LLR_MAX);
                float s = ((W[8191] + msg[2][0]) + t5c1) - x;
                if (last) out_b[13653] = -s; else sh32[5461] = s;
            }
        }
        __syncthreads();

        // ---- E-t4  ||  stage t5 -> W ----
#pragma unroll
        for (int i = 0; i < 8; ++i) W[tid + THREADS * i] = msg[2][i];
        if (!last) {
#pragma unroll
            for (int i = 0; i < 8; ++i) {
                int c = tid + THREADS * i;
                int e = c + 32768;
                int v = (int)(((unsigned)e * 43691u) >> 17);
                float m = sh32[v - 8192] - msg[1][i];
                unsigned neg = (m < 0.0f) ? 1u : 0u;
                unsigned bit = neg << ((unsigned)(i & 3) * 6 + 4);
                if (i < 4) sbA |= bit; else sbB |= bit;
                float mg = phi_f(fabsf(m));
                msg[1][i] = mg;
                ms[i] = ms[i] + mg;
                __builtin_amdgcn_sched_barrier(0);
            }
        }
        __syncthreads();

        // ---- chunk t5: v in [13654,16384) ----
#pragma unroll
        for (int k = 0; k < 3; ++k) {
            int r = tid + THREADS * k;
            if (r < 2730) {
                int v = 13654 + r;
                float x = fminf(fmaxf(lp[v], -LLR_MAX), LLR_MAX);
                int j = 3 * r + 2;
                float s = ((W[j] + W[j + 1]) + W[j + 2]) - x;
                if (last) out_b[v] = -s; else sh32[5462 + r] = s;
            }
        }
        __syncthreads();

        if (!last) {
            // ---- E-t5 ----
#pragma unroll
            for (int i = 0; i < 8; ++i) {
                int c = tid + THREADS * i;
                int e = c + 40960;
                int v = (int)(((unsigned)e * 43691u) >> 17);
                float m = sh32[v - 8192] - msg[2][i];
                unsigned neg = (m < 0.0f) ? 1u : 0u;
                unsigned bit = neg << ((unsigned)(i & 3) * 6 + 5);
                if (i < 4) sbA |= bit; else sbB |= bit;
                float mg = phi_f(fabsf(m));
                msg[2][i] = mg;
                ms[i] = ms[i] + mg;
                __builtin_amdgcn_sched_barrier(0);
            }
            // ---- second pass: new messages (own slots/regs only) ----
#pragma unroll
            for (int i = 0; i < 8; ++i) {
                int c = tid + THREADS * i;
                unsigned f = ((i < 4 ? sbA : sbB) >> ((unsigned)(i & 3) * 6)) & 63u;
                unsigned all6 = __popc(f) & 1u;
#pragma unroll
                for (int t = 0; t < 3; ++t) {
                    int e = c + (t << 13);
                    float mg = buf[e];
                    float o = phi_f(ms[i] - mg);
                    unsigned flip = all6 ^ ((f >> t) & 1u);
                    buf[e] = flip ? -o : o;
                    __builtin_amdgcn_sched_barrier(0);
                }
#pragma unroll
                for (int tb = 0; tb < 3; ++tb) {
                    float mg = msg[tb][i];
                    float o = phi_f(ms[i] - mg);
                    unsigned flip = all6 ^ ((f >> (tb + 3)) & 1u);
                    msg[tb][i] = flip ? -o : o;
                    __builtin_amdgcn_sched_barrier(0);
                }
            }
        }
    }
}

extern "C" void kernel_launch(void* const* d_in, const int* in_sizes, int n_in,
                              void* d_out, int out_size, void* d_ws, size_t ws_size,
                              hipStream_t stream) {
    const float* llr_ch = (const float*)d_in[0];
    float* out = (float*)d_out;
    ldpc_bp_kernel<<<dim3(128), dim3(THREADS), 0, stream>>>(llr_ch, out);
}